// Round 3
// baseline (1339.244 us; speedup 1.0000x reference)
//
#include <hip/hip_runtime.h>

namespace {

constexpr int N = 20;                  // NEIGHBOR_SIZE
constexpr int ROWS = 5;                // rows per lane
constexpr int GROUPS = 16;             // 4-lane groups per wave -> 16 matrices/wave
constexpr int WAVES_PER_BLOCK = 4;     // 256 threads
constexpr int MATS_PER_BLOCK = GROUPS * WAVES_PER_BLOCK;  // 64
constexpr int SLOT = 36;               // row-slot stride in floats (20 + 16 pad):
                                       // 36*g mod 32 = 4g -> 16 groups on 16 banks,
                                       // b128 spans make it 2-way max = free (m136)
constexpr float SIGMA_SQ = 1.0f;
constexpr float PHI = 0.5f;
constexpr float TAU = 0.1f;

// 4 lanes per matrix; lane o of a group owns rows 5o..5o+4 in registers.
// Per GJ step k the owner lane publishes row k via LDS (5x ds_write_b128,
// 16 owner lanes across the wave = full-bandwidth write); everyone reads it
// back as 5x ds_read_b128 (4-lane broadcast groups, padded slots).
__global__ __launch_bounds__(256, 2) void invcov_kernel(
    const float* __restrict__ pos, float* __restrict__ out, int B) {
  __shared__ float lds[WAVES_PER_BLOCK][GROUPS * SLOT];

  const int tid  = threadIdx.x;
  const int wave = tid >> 6;
  const int lane = tid & 63;
  const int g    = lane >> 2;          // group (matrix) within wave, 0..15
  const int o    = lane & 3;           // owner id within group, rows 5o..5o+4
  const int m    = blockIdx.x * MATS_PER_BLOCK + wave * GROUPS + g;
  const int mc   = (m < B) ? m : (B - 1);
  float* slot = &lds[wave][g * SLOT];

  const float* pm = pos + (size_t)mc * (2 * N);

  // All 20 points into registers (compile-time indexed; 4 lanes of a group
  // read the same addresses -> broadcast, L1-served).
  float px[N], py[N];
  {
    const float4* pv = (const float4*)pm;
#pragma unroll
    for (int q = 0; q < N / 2; ++q) {
      const float4 p = pv[q];
      px[2 * q]     = p.x; py[2 * q]     = p.y;
      px[2 * q + 1] = p.z; py[2 * q + 1] = p.w;
    }
  }
  // My 5 rows' own points (runtime offset 5o+rr -> tiny L1-hit loads).
  float myx[ROWS], myy[ROWS];
  {
    const float2* pm2 = (const float2*)pm;
#pragma unroll
    for (int rr = 0; rr < ROWS; ++rr) {
      const float2 p = pm2[5 * o + rr];
      myx[rr] = p.x; myy[rr] = p.y;
    }
  }

  // Build my 5 rows of cov: a[rr][c] = s^2 exp(-phi*d) + tau*s^2*[c==row]
  float a[ROWS][N];
#pragma unroll
  for (int rr = 0; rr < ROWS; ++rr) {
    const int i = 5 * o + rr;  // runtime row index (only used in compares)
#pragma unroll
    for (int c = 0; c < N; ++c) {
      const float dx = px[c] - myx[rr];
      const float dy = py[c] - myy[rr];
      const float d  = sqrtf(__builtin_fmaf(dx, dx, dy * dy));
      float v = SIGMA_SQ * __expf(-PHI * d);
      if (c == i) v += TAU * SIGMA_SQ;   // c compile-time, i runtime -> cndmask
      a[rr][c] = v;
    }
  }

  // In-place Gauss-Jordan (SPD + nugget -> no pivoting).
#pragma unroll
  for (int k = 0; k < N; ++k) {
    const int ko = k / 5;   // owner lane of row k (compile-time)
    const int kr = k % 5;   // local row index at owner (compile-time)

    if (o == ko) {  // publish current row k
      *(float4*)&slot[0]  = make_float4(a[kr][0],  a[kr][1],  a[kr][2],  a[kr][3]);
      *(float4*)&slot[4]  = make_float4(a[kr][4],  a[kr][5],  a[kr][6],  a[kr][7]);
      *(float4*)&slot[8]  = make_float4(a[kr][8],  a[kr][9],  a[kr][10], a[kr][11]);
      *(float4*)&slot[12] = make_float4(a[kr][12], a[kr][13], a[kr][14], a[kr][15]);
      *(float4*)&slot[16] = make_float4(a[kr][16], a[kr][17], a[kr][18], a[kr][19]);
    }
    asm volatile("s_waitcnt lgkmcnt(0)" ::: "memory");

    const float4 q0 = *(const float4*)&slot[0];
    const float4 q1 = *(const float4*)&slot[4];
    const float4 q2 = *(const float4*)&slot[8];
    const float4 q3 = *(const float4*)&slot[12];
    const float4 q4 = *(const float4*)&slot[16];
    const float r[N] = {q0.x, q0.y, q0.z, q0.w, q1.x, q1.y, q1.z, q1.w,
                        q2.x, q2.y, q2.z, q2.w, q3.x, q3.y, q3.z, q3.w,
                        q4.x, q4.y, q4.z, q4.w};
    const float ip = __builtin_amdgcn_rcpf(r[k]);

#pragma unroll
    for (int rr = 0; rr < ROWS; ++rr) {
      if (rr == kr) {
        // Only this rr can be the pivot row; runtime-divergent on o (16/48).
        if (o == ko) {
#pragma unroll
          for (int j = 0; j < N; ++j) a[rr][j] = (j == k) ? ip : r[j] * ip;
        } else {
          const float f = a[rr][k] * ip;
#pragma unroll
          for (int j = 0; j < N; ++j)
            a[rr][j] = (j == k) ? -f : __builtin_fmaf(-f, r[j], a[rr][j]);
        }
      } else {
        const float f = a[rr][k] * ip;
#pragma unroll
        for (int j = 0; j < N; ++j)
          a[rr][j] = (j == k) ? -f : __builtin_fmaf(-f, r[j], a[rr][j]);
      }
    }
  }

  // Store my 5 rows (float4 x 25, scattered but line-dense per matrix).
  if (m < B) {
    float* om = out + (size_t)m * (N * N);
#pragma unroll
    for (int rr = 0; rr < ROWS; ++rr) {
      float* orow = om + (5 * o + rr) * N;
      *(float4*)&orow[0]  = make_float4(a[rr][0],  a[rr][1],  a[rr][2],  a[rr][3]);
      *(float4*)&orow[4]  = make_float4(a[rr][4],  a[rr][5],  a[rr][6],  a[rr][7]);
      *(float4*)&orow[8]  = make_float4(a[rr][8],  a[rr][9],  a[rr][10], a[rr][11]);
      *(float4*)&orow[12] = make_float4(a[rr][12], a[rr][13], a[rr][14], a[rr][15]);
      *(float4*)&orow[16] = make_float4(a[rr][16], a[rr][17], a[rr][18], a[rr][19]);
    }
  }
}

}  // namespace

extern "C" void kernel_launch(void* const* d_in, const int* in_sizes, int n_in,
                              void* d_out, int out_size, void* d_ws, size_t ws_size,
                              hipStream_t stream) {
  const float* pos = (const float*)d_in[0];   // [B, 40] f32
  // d_in[1] (edge_list, int64) is unused by the reference computation.
  float* out = (float*)d_out;                 // [B, 20, 20] f32
  const int B = in_sizes[0] / (2 * N);
  const int blocks = (B + MATS_PER_BLOCK - 1) / MATS_PER_BLOCK;
  invcov_kernel<<<blocks, 256, 0, stream>>>(pos, out, B);
}

// Round 4
// 141.715 us; speedup vs baseline: 9.4503x; 9.4503x over previous
//
#include <hip/hip_runtime.h>

namespace {

constexpr int N = 20;                  // NEIGHBOR_SIZE
constexpr int ROWS = 5;                // rows per lane
constexpr int GROUPS = 16;             // 4-lane quads per wave = 16 matrices/wave
constexpr int WAVES_PER_BLOCK = 4;     // 256 threads
constexpr int MATS_PER_BLOCK = GROUPS * WAVES_PER_BLOCK;  // 64 (200000 % 64 == 0... 3125 blocks exact)
constexpr float SIGMA_SQ = 1.0f;
constexpr float PHI = 0.5f;
constexpr float TAU = 0.1f;

// Broadcast lane SRC of each 4-lane quad to all 4 lanes: DPP quad_perm,
// pure VALU (per-SIMD pipe) -- no LDS traffic at all.
template <int SRC>
__device__ __forceinline__ float qbcast(float x) {
  constexpr int CTRL = SRC * 0x55;     // quad_perm:[SRC,SRC,SRC,SRC]
  return __builtin_bit_cast(
      float, __builtin_amdgcn_mov_dpp(__builtin_bit_cast(int, x), CTRL, 0xF,
                                      0xF, true));
}

// One Gauss-Jordan elimination step. K is a TEMPLATE parameter so every
// array index (K, K/5, K%5) is compile-time regardless of unroll heuristics
// -- scratch-proof (rule #20; R3's regression was exactly this).
// Unified branch-free update: for the pivot row on the owner lane we use
// f = 1 - 1/p, which makes  a[j] - f*r[j] = r[j]/p  (since a==r there), plus
// a single +1 diagonal fixup. All other rows use the normal f = a[K]/p.
template <int K>
__device__ __forceinline__ void gj_step(float (&a)[ROWS][N], int o,
                                        const float (&ofl)[4]) {
  constexpr int KO = K / ROWS;         // owner lane of row K (compile-time)
  constexpr int KR = K % ROWS;         // owner-local row index (compile-time)
  float r[N];
#pragma unroll
  for (int j = 0; j < N; ++j) r[j] = qbcast<KO>(a[KR][j]);
  const float ip = __builtin_amdgcn_rcpf(r[K]);
  const float fpiv = 1.0f - ip;
#pragma unroll
  for (int rr = 0; rr < ROWS; ++rr) {
    float f = a[rr][K] * ip;
    if (rr == KR) f = (o == KO) ? fpiv : f;  // one cndmask, only on row KR
    const float nf = -f;
#pragma unroll
    for (int j = 0; j < N; ++j) {
      if (j == K) continue;
      a[rr][j] = __builtin_fmaf(nf, r[j], a[rr][j]);
    }
    a[rr][K] = nf;                     // column K: -A[i][K]/p
  }
  a[KR][K] += ofl[KO];                 // owner diag: (ip-1)+1 = ip
}

__global__ __launch_bounds__(256, 2) void invcov_kernel(
    const float* __restrict__ pos, float* __restrict__ out, int B) {
  const int tid  = threadIdx.x;
  const int lane = tid & 63;
  const int wave = tid >> 6;
  const int g    = lane >> 2;          // quad = matrix within wave, 0..15
  const int o    = lane & 3;           // lane within quad, owns rows 5o..5o+4
  const int m    = blockIdx.x * MATS_PER_BLOCK + wave * GROUPS + g;
  const int mc   = (m < B) ? m : (B - 1);

  const float* pm = pos + (size_t)mc * (2 * N);

  // All 20 points in registers (compile-time indexed).
  float px[N], py[N];
  {
    const float4* pv = (const float4*)pm;
#pragma unroll
    for (int q = 0; q < N / 2; ++q) {
      const float4 p = pv[q];
      px[2 * q]     = p.x; py[2 * q]     = p.y;
      px[2 * q + 1] = p.z; py[2 * q + 1] = p.w;
    }
  }
  // My 5 rows' coords: runtime offset -> load from memory (L1-hit), NOT a
  // runtime index into the px/py register arrays.
  float myx[ROWS], myy[ROWS];
  {
    const float2* pm2 = (const float2*)pm;
#pragma unroll
    for (int rr = 0; rr < ROWS; ++rr) {
      const float2 p = pm2[ROWS * o + rr];
      myx[rr] = p.x; myy[rr] = p.y;
    }
  }

  // Per-quad-lane constant masks, always constant-indexed.
  float tdiag[4], ofl[4];
#pragma unroll
  for (int t = 0; t < 4; ++t) {
    const bool is = (o == t);
    tdiag[t] = is ? (TAU * SIGMA_SQ) : 0.0f;
    ofl[t]   = is ? 1.0f : 0.0f;
  }

  // Build my 5 rows: a[rr][c] = s^2 exp(-phi*d) (+ tau*s^2 on my diagonal).
  // Diagonal test: global row = 5o+rr, so (c==row) <=> (c%5==rr && o==c/5);
  // c,rr compile-time -> only 20 of 100 elements carry a (constant-indexed)
  // masked add.
  float a[ROWS][N];
#pragma unroll
  for (int rr = 0; rr < ROWS; ++rr) {
#pragma unroll
    for (int c = 0; c < N; ++c) {
      const float dx = px[c] - myx[rr];
      const float dy = py[c] - myy[rr];
      const float d  = __builtin_amdgcn_sqrtf(__builtin_fmaf(dx, dx, dy * dy));
      float v = SIGMA_SQ * __expf(-PHI * d);
      if (c % ROWS == rr) v += tdiag[c / ROWS];
      a[rr][c] = v;
    }
  }

  // 20 explicit template steps: guaranteed compile-time K everywhere.
  gj_step<0>(a, o, ofl);  gj_step<1>(a, o, ofl);  gj_step<2>(a, o, ofl);
  gj_step<3>(a, o, ofl);  gj_step<4>(a, o, ofl);  gj_step<5>(a, o, ofl);
  gj_step<6>(a, o, ofl);  gj_step<7>(a, o, ofl);  gj_step<8>(a, o, ofl);
  gj_step<9>(a, o, ofl);  gj_step<10>(a, o, ofl); gj_step<11>(a, o, ofl);
  gj_step<12>(a, o, ofl); gj_step<13>(a, o, ofl); gj_step<14>(a, o, ofl);
  gj_step<15>(a, o, ofl); gj_step<16>(a, o, ofl); gj_step<17>(a, o, ofl);
  gj_step<18>(a, o, ofl); gj_step<19>(a, o, ofl);

  // Store my 5 contiguous rows (400 B per lane, 1.6 KB dense per quad).
  if (m < B) {
    float* om = out + (size_t)m * (N * N) + (ROWS * o) * N;
#pragma unroll
    for (int rr = 0; rr < ROWS; ++rr) {
#pragma unroll
      for (int q = 0; q < N / 4; ++q) {
        *(float4*)&om[rr * N + 4 * q] =
            make_float4(a[rr][4 * q], a[rr][4 * q + 1], a[rr][4 * q + 2],
                        a[rr][4 * q + 3]);
      }
    }
  }
}

}  // namespace

extern "C" void kernel_launch(void* const* d_in, const int* in_sizes, int n_in,
                              void* d_out, int out_size, void* d_ws, size_t ws_size,
                              hipStream_t stream) {
  const float* pos = (const float*)d_in[0];   // [B, 40] f32
  // d_in[1] (edge_list, int64) is unused by the reference computation.
  float* out = (float*)d_out;                 // [B, 20, 20] f32
  const int B = in_sizes[0] / (2 * N);
  const int blocks = (B + MATS_PER_BLOCK - 1) / MATS_PER_BLOCK;
  invcov_kernel<<<blocks, 256, 0, stream>>>(pos, out, B);
}

// Round 5
// 92.009 us; speedup vs baseline: 14.5556x; 1.5402x over previous
//
#include <hip/hip_runtime.h>

namespace {

constexpr int N = 20;                  // NEIGHBOR_SIZE
constexpr int ROWS = 5;                // rows per lane
constexpr int GROUPS = 16;             // 4-lane quads per wave = 16 matrices/wave
constexpr int WAVES_PER_BLOCK = 4;     // 256 threads
constexpr int MATS_PER_BLOCK = GROUPS * WAVES_PER_BLOCK;  // 64 -> 3125 blocks exact
constexpr float SIGMA_SQ = 1.0f;
constexpr float PHI = 0.5f;
constexpr float TAU = 0.1f;

// Broadcast lane SRC of each 4-lane quad to all 4 lanes: DPP quad_perm,
// pure VALU (per-SIMD pipe) -- no LDS traffic.
template <int SRC>
__device__ __forceinline__ float qbcast(float x) {
  constexpr int CTRL = SRC * 0x55;     // quad_perm:[SRC,SRC,SRC,SRC]
  return __builtin_bit_cast(
      float, __builtin_amdgcn_mov_dpp(__builtin_bit_cast(int, x), CTRL, 0xF,
                                      0xF, true));
}

// One Gauss-Jordan elimination step; K is a template parameter so every
// array index is compile-time regardless of unroll heuristics (rule #20).
template <int K>
__device__ __forceinline__ void gj_step(float (&a)[ROWS][N], int o,
                                        const float (&ofl)[4]) {
  constexpr int KO = K / ROWS;         // owner lane of row K
  constexpr int KR = K % ROWS;         // owner-local row index
  float r[N];
#pragma unroll
  for (int j = 0; j < N; ++j) r[j] = qbcast<KO>(a[KR][j]);
  const float ip = __builtin_amdgcn_rcpf(r[K]);
  const float fpiv = 1.0f - ip;
#pragma unroll
  for (int rr = 0; rr < ROWS; ++rr) {
    float f = a[rr][K] * ip;
    if (rr == KR) f = (o == KO) ? fpiv : f;  // one cndmask, only on row KR
    const float nf = -f;
#pragma unroll
    for (int j = 0; j < N; ++j) {
      if (j == K) continue;
      a[rr][j] = __builtin_fmaf(nf, r[j], a[rr][j]);
    }
    a[rr][K] = nf;                     // column K: -A[i][K]/p
  }
  a[KR][K] += ofl[KO];                 // owner diag: (1/p - 1) + 1 = 1/p
}

__global__ __launch_bounds__(256, 2) void invcov_kernel(
    const float* __restrict__ pos, float* __restrict__ out, int B) {
  // Per-wave 6.4 KB transpose buffer (4 matrices x 400 floats), reused over
  // 4 passes. Wave-local use only -> lgkmcnt ordering, no barriers.
  __shared__ float lds[WAVES_PER_BLOCK][4 * N * N];

  const int tid  = threadIdx.x;
  const int lane = tid & 63;
  const int wave = tid >> 6;
  const int g    = lane >> 2;          // quad = matrix within wave, 0..15
  const int o    = lane & 3;           // lane within quad, owns rows 5o..5o+4
  const int mwave0 = blockIdx.x * MATS_PER_BLOCK + wave * GROUPS;
  const int m    = mwave0 + g;
  const int mc   = (m < B) ? m : (B - 1);

  const float* pm = pos + (size_t)mc * (2 * N);

  // All 20 points in registers (compile-time indexed).
  float px[N], py[N];
  {
    const float4* pv = (const float4*)pm;
#pragma unroll
    for (int q = 0; q < N / 2; ++q) {
      const float4 p = pv[q];
      px[2 * q]     = p.x; py[2 * q]     = p.y;
      px[2 * q + 1] = p.z; py[2 * q + 1] = p.w;
    }
  }
  // My 5 rows' coords: runtime offset -> tiny L1-hit loads, not reg-indexing.
  float myx[ROWS], myy[ROWS];
  {
    const float2* pm2 = (const float2*)pm;
#pragma unroll
    for (int rr = 0; rr < ROWS; ++rr) {
      const float2 p = pm2[ROWS * o + rr];
      myx[rr] = p.x; myy[rr] = p.y;
    }
  }

  // Per-quad-lane constant masks, constant-indexed.
  float tdiag[4], ofl[4];
#pragma unroll
  for (int t = 0; t < 4; ++t) {
    const bool is = (o == t);
    tdiag[t] = is ? (TAU * SIGMA_SQ) : 0.0f;
    ofl[t]   = is ? 1.0f : 0.0f;
  }

  // Build my 5 rows: a[rr][c] = s^2 exp(-phi*d) (+ tau*s^2 on my diagonal).
  float a[ROWS][N];
#pragma unroll
  for (int rr = 0; rr < ROWS; ++rr) {
#pragma unroll
    for (int c = 0; c < N; ++c) {
      const float dx = px[c] - myx[rr];
      const float dy = py[c] - myy[rr];
      const float d  = __builtin_amdgcn_sqrtf(__builtin_fmaf(dx, dx, dy * dy));
      float v = SIGMA_SQ * __expf(-PHI * d);
      if (c % ROWS == rr) v += tdiag[c / ROWS];
      a[rr][c] = v;
    }
  }

  // 20 explicit template steps: compile-time K everywhere.
  gj_step<0>(a, o, ofl);  gj_step<1>(a, o, ofl);  gj_step<2>(a, o, ofl);
  gj_step<3>(a, o, ofl);  gj_step<4>(a, o, ofl);  gj_step<5>(a, o, ofl);
  gj_step<6>(a, o, ofl);  gj_step<7>(a, o, ofl);  gj_step<8>(a, o, ofl);
  gj_step<9>(a, o, ofl);  gj_step<10>(a, o, ofl); gj_step<11>(a, o, ofl);
  gj_step<12>(a, o, ofl); gj_step<13>(a, o, ofl); gj_step<14>(a, o, ofl);
  gj_step<15>(a, o, ofl); gj_step<16>(a, o, ofl); gj_step<17>(a, o, ofl);
  gj_step<18>(a, o, ofl); gj_step<19>(a, o, ofl);

  float* wbuf = &lds[wave][0];

  if (mwave0 + GROUPS <= B) {
    // Dense epilogue: 4 passes of 4 matrices. Owning 16 lanes stage 400 B
    // each into LDS; all 64 lanes store the 6400 B chunk back contiguously
    // (1 KB per store instruction -> full-sector HBM writes).
#pragma unroll
    for (int p = 0; p < 4; ++p) {
      if ((g >> 2) == p) {
        float* dst = wbuf + (g & 3) * (N * N) + o * (ROWS * N);
#pragma unroll
        for (int rr = 0; rr < ROWS; ++rr) {
#pragma unroll
          for (int q = 0; q < N / 4; ++q) {
            *(float4*)&dst[rr * N + 4 * q] =
                make_float4(a[rr][4 * q], a[rr][4 * q + 1], a[rr][4 * q + 2],
                            a[rr][4 * q + 3]);
          }
        }
      }
      asm volatile("s_waitcnt lgkmcnt(0)" ::: "memory");

      float* gout = out + (size_t)(mwave0 + 4 * p) * (N * N);
#pragma unroll
      for (int t = 0; t < 6; ++t) {
        const float4 v = *(const float4*)&wbuf[lane * 4 + t * 256];
        *(float4*)&gout[lane * 4 + t * 256] = v;
      }
      if (lane < 16) {
        const float4 v = *(const float4*)&wbuf[lane * 4 + 6 * 256];
        *(float4*)&gout[lane * 4 + 6 * 256] = v;
      }
      // Reads must land in VGPRs before next pass overwrites the buffer.
      asm volatile("s_waitcnt lgkmcnt(0)" ::: "memory");
    }
  } else if (m < B) {
    // Rare tail wave: direct (slow) per-lane stores.
    float* om = out + (size_t)m * (N * N) + (ROWS * o) * N;
#pragma unroll
    for (int rr = 0; rr < ROWS; ++rr) {
#pragma unroll
      for (int q = 0; q < N / 4; ++q) {
        *(float4*)&om[rr * N + 4 * q] =
            make_float4(a[rr][4 * q], a[rr][4 * q + 1], a[rr][4 * q + 2],
                        a[rr][4 * q + 3]);
      }
    }
  }
}

}  // namespace

extern "C" void kernel_launch(void* const* d_in, const int* in_sizes, int n_in,
                              void* d_out, int out_size, void* d_ws, size_t ws_size,
                              hipStream_t stream) {
  const float* pos = (const float*)d_in[0];   // [B, 40] f32
  // d_in[1] (edge_list, int64) is unused by the reference computation.
  float* out = (float*)d_out;                 // [B, 20, 20] f32
  const int B = in_sizes[0] / (2 * N);
  const int blocks = (B + MATS_PER_BLOCK - 1) / MATS_PER_BLOCK;
  invcov_kernel<<<blocks, 256, 0, stream>>>(pos, out, B);
}

// Round 8
// 91.030 us; speedup vs baseline: 14.7121x; 1.0108x over previous
//
#include <hip/hip_runtime.h>

namespace {

constexpr int N = 20;                  // NEIGHBOR_SIZE
constexpr int ROWS = 5;                // rows per lane
constexpr int GROUPS = 16;             // 4-lane quads per wave = 16 matrices/wave
constexpr int WAVES_PER_BLOCK = 4;     // 256 threads
constexpr int MATS_PER_BLOCK = GROUPS * WAVES_PER_BLOCK;  // 64 -> 3125 blocks exact
constexpr float SIGMA_SQ = 1.0f;
constexpr float PHI = 0.5f;
constexpr float TAU = 0.1f;
// exp(-phi*d) = 2^(-phi*log2(e)*d): pre-scale coords by C = phi*log2(e); the
// negate folds into the v_exp_f32 input modifier.
constexpr float CSCALE = 0.72134752f;  // PHI * log2(e)

// Broadcast lane SRC of each 4-lane quad to all 4 lanes: DPP quad_perm,
// pure VALU (per-SIMD pipe) -- no LDS traffic.
template <int SRC>
__device__ __forceinline__ float qbcast(float x) {
  constexpr int CTRL = SRC * 0x55;     // quad_perm:[SRC,SRC,SRC,SRC]
  return __builtin_bit_cast(
      float, __builtin_amdgcn_mov_dpp(__builtin_bit_cast(int, x), CTRL, 0xF,
                                      0xF, true));
}

// One Gauss-Jordan elimination step; K is a template parameter so every
// array index is compile-time regardless of unroll heuristics (rule #20).
template <int K>
__device__ __forceinline__ void gj_step(float (&a)[ROWS][N], int o,
                                        const float (&ofl)[4]) {
  constexpr int KO = K / ROWS;         // owner lane of row K
  constexpr int KR = K % ROWS;         // owner-local row index
  float r[N];
#pragma unroll
  for (int j = 0; j < N; ++j) r[j] = qbcast<KO>(a[KR][j]);
  const float ip = __builtin_amdgcn_rcpf(r[K]);
  const float fpiv = 1.0f - ip;
#pragma unroll
  for (int rr = 0; rr < ROWS; ++rr) {
    float f = a[rr][K] * ip;
    if (rr == KR) f = (o == KO) ? fpiv : f;  // one cndmask, only on row KR
    const float nf = -f;
#pragma unroll
    for (int j = 0; j < N; ++j) {
      if (j == K) continue;
      a[rr][j] = __builtin_fmaf(nf, r[j], a[rr][j]);
    }
    a[rr][K] = nf;                     // column K: -A[i][K]/p
  }
  a[KR][K] += ofl[KO];                 // owner diag: (1/p - 1) + 1 = 1/p
}

__global__ __launch_bounds__(256, 2) void invcov_kernel(
    const float* __restrict__ pos, float* __restrict__ out, int B) {
  // Per-wave 6.4 KB transpose buffer (4 matrices x 400 floats), reused over
  // 4 passes. Wave-local only -> lgkmcnt fences (no barriers). R7 lesson:
  // the explicit fences ARE required -- removing them broke ordering.
  __shared__ float lds[WAVES_PER_BLOCK][4 * N * N];

  const int tid  = threadIdx.x;
  const int lane = tid & 63;
  const int wave = tid >> 6;
  const int g    = lane >> 2;          // quad = matrix within wave, 0..15
  const int o    = lane & 3;           // lane within quad, owns rows 5o..5o+4
  const int mwave0 = blockIdx.x * MATS_PER_BLOCK + wave * GROUPS;
  const int m    = mwave0 + g;
  const int mc   = (m < B) ? m : (B - 1);

  const float* pm = pos + (size_t)mc * (2 * N);

  // All 20 points in registers, pre-scaled by CSCALE (compile-time indexed).
  float px[N], py[N];
  {
    const float4* pv = (const float4*)pm;
#pragma unroll
    for (int q = 0; q < N / 2; ++q) {
      const float4 p = pv[q];
      px[2 * q]     = p.x * CSCALE; py[2 * q]     = p.y * CSCALE;
      px[2 * q + 1] = p.z * CSCALE; py[2 * q + 1] = p.w * CSCALE;
    }
  }
  // My 5 rows' coords: runtime offset -> tiny L1-hit loads, not reg-indexing.
  float myx[ROWS], myy[ROWS];
  {
    const float2* pm2 = (const float2*)pm;
#pragma unroll
    for (int rr = 0; rr < ROWS; ++rr) {
      const float2 p = pm2[ROWS * o + rr];
      myx[rr] = p.x * CSCALE; myy[rr] = p.y * CSCALE;
    }
  }

  // Per-quad-lane constant masks, constant-indexed.
  float tdiag[4], ofl[4];
#pragma unroll
  for (int t = 0; t < 4; ++t) {
    const bool is = (o == t);
    tdiag[t] = is ? (TAU * SIGMA_SQ) : 0.0f;
    ofl[t]   = is ? 1.0f : 0.0f;
  }

  // Build my 5 rows: a[rr][c] = s^2 * 2^(-C*d) (+ tau*s^2 on my diagonal).
  float a[ROWS][N];
#pragma unroll
  for (int rr = 0; rr < ROWS; ++rr) {
#pragma unroll
    for (int c = 0; c < N; ++c) {
      const float dx = px[c] - myx[rr];
      const float dy = py[c] - myy[rr];
      const float t  = __builtin_amdgcn_sqrtf(__builtin_fmaf(dx, dx, dy * dy));
      float v = SIGMA_SQ * __builtin_amdgcn_exp2f(-t);  // neg -> input modifier
      if (c % ROWS == rr) v += tdiag[c / ROWS];
      a[rr][c] = v;
    }
  }

  // 20 explicit template steps: compile-time K everywhere. setprio(1) gives
  // GJ-phase waves issue priority over build/epilogue-phase waves on the same
  // SIMD -- our waves are barrier-free/independent.
  __builtin_amdgcn_s_setprio(1);
  gj_step<0>(a, o, ofl);  gj_step<1>(a, o, ofl);  gj_step<2>(a, o, ofl);
  gj_step<3>(a, o, ofl);  gj_step<4>(a, o, ofl);  gj_step<5>(a, o, ofl);
  gj_step<6>(a, o, ofl);  gj_step<7>(a, o, ofl);  gj_step<8>(a, o, ofl);
  gj_step<9>(a, o, ofl);  gj_step<10>(a, o, ofl); gj_step<11>(a, o, ofl);
  gj_step<12>(a, o, ofl); gj_step<13>(a, o, ofl); gj_step<14>(a, o, ofl);
  gj_step<15>(a, o, ofl); gj_step<16>(a, o, ofl); gj_step<17>(a, o, ofl);
  gj_step<18>(a, o, ofl); gj_step<19>(a, o, ofl);
  __builtin_amdgcn_s_setprio(0);

  float* wbuf = &lds[wave][0];

  if (mwave0 + GROUPS <= B) {
    // Dense epilogue: 4 passes of 4 matrices. Owning 16 lanes stage 400 B
    // each into LDS; all 64 lanes store the 6400 B chunk back contiguously
    // (1 KB per store instruction -> full-sector HBM writes).
#pragma unroll
    for (int p = 0; p < 4; ++p) {
      if ((g >> 2) == p) {
        float* dst = wbuf + (g & 3) * (N * N) + o * (ROWS * N);
#pragma unroll
        for (int rr = 0; rr < ROWS; ++rr) {
#pragma unroll
          for (int q = 0; q < N / 4; ++q) {
            *(float4*)&dst[rr * N + 4 * q] =
                make_float4(a[rr][4 * q], a[rr][4 * q + 1], a[rr][4 * q + 2],
                            a[rr][4 * q + 3]);
          }
        }
      }
      asm volatile("s_waitcnt lgkmcnt(0)" ::: "memory");

      float* gout = out + (size_t)(mwave0 + 4 * p) * (N * N);
#pragma unroll
      for (int t = 0; t < 6; ++t) {
        const float4 v = *(const float4*)&wbuf[lane * 4 + t * 256];
        *(float4*)&gout[lane * 4 + t * 256] = v;
      }
      if (lane < 16) {
        const float4 v = *(const float4*)&wbuf[lane * 4 + 6 * 256];
        *(float4*)&gout[lane * 4 + 6 * 256] = v;
      }
      // Reads must land in VGPRs before next pass overwrites the buffer.
      asm volatile("s_waitcnt lgkmcnt(0)" ::: "memory");
    }
  } else if (m < B) {
    // Rare tail wave: direct (slow) per-lane stores.
    float* om = out + (size_t)m * (N * N) + (ROWS * o) * N;
#pragma unroll
    for (int rr = 0; rr < ROWS; ++rr) {
#pragma unroll
      for (int q = 0; q < N / 4; ++q) {
        *(float4*)&om[rr * N + 4 * q] =
            make_float4(a[rr][4 * q], a[rr][4 * q + 1], a[rr][4 * q + 2],
                        a[rr][4 * q + 3]);
      }
    }
  }
}

}  // namespace

extern "C" void kernel_launch(void* const* d_in, const int* in_sizes, int n_in,
                              void* d_out, int out_size, void* d_ws, size_t ws_size,
                              hipStream_t stream) {
  const float* pos = (const float*)d_in[0];   // [B, 40] f32
  // d_in[1] (edge_list, int64) is unused by the reference computation.
  float* out = (float*)d_out;                 // [B, 20, 20] f32
  const int B = in_sizes[0] / (2 * N);
  const int blocks = (B + MATS_PER_BLOCK - 1) / MATS_PER_BLOCK;
  invcov_kernel<<<blocks, 256, 0, stream>>>(pos, out, B);
}